// Round 10
// baseline (100.100 us; speedup 1.0000x reference)
//
#include <hip/hip_runtime.h>
#include <stdint.h>

#define B_ 4096
#define D_ 1024
#define BM 256
#define BN 128
#define BK 32
#define NT 32            // K tiles (1024 / 32)
#define TINV 10.0f
#define LOG2E 1.4426950408889634f
#define KE (TINV * LOG2E)
#define INV_BM1 (1.0f / 4095.0f)
#define NBX 32           // B_/BN (row-partial planes)
#define NBY 16           // B_/BM (col-partial planes)

typedef __bf16 bf16x8 __attribute__((ext_vector_type(8)));
typedef float f32x4 __attribute__((ext_vector_type(4)));

__device__ __forceinline__ unsigned short f2bf(float x) {
  uint32_t b = __float_as_uint(x);
  b += 0x7FFF + ((b >> 16) & 1);   // RNE
  return (unsigned short)(b >> 16);
}

__device__ __forceinline__ void gload16(const void* g, void* l) {
  __builtin_amdgcn_global_load_lds(
      (const __attribute__((address_space(1))) uint32_t*)g,
      (__attribute__((address_space(3))) uint32_t*)l, 16, 0, 0);
}

// ---------------- K1: L2-normalize rows, emit bf16 ----------------
__global__ __launch_bounds__(256) void k_normalize(const float* __restrict__ zis,
                                                   const float* __restrict__ zjs,
                                                   unsigned short* __restrict__ Abf,
                                                   unsigned short* __restrict__ Bbf) {
  int r = blockIdx.x;
  const float* src;
  unsigned short* dst;
  if (r < B_) { src = zis + (size_t)r * D_; dst = Abf + (size_t)r * D_; }
  else        { src = zjs + (size_t)(r - B_) * D_; dst = Bbf + (size_t)(r - B_) * D_; }
  int t = threadIdx.x;
  float4 v = reinterpret_cast<const float4*>(src)[t];
  float ss = v.x*v.x + v.y*v.y + v.z*v.z + v.w*v.w;
  #pragma unroll
  for (int o = 32; o >= 1; o >>= 1) ss += __shfl_down(ss, o);
  __shared__ float red[4];
  if ((t & 63) == 0) red[t >> 6] = ss;
  __syncthreads();
  float sc = rsqrtf(red[0] + red[1] + red[2] + red[3]);
  ushort4 o4;
  o4.x = f2bf(v.x * sc); o4.y = f2bf(v.y * sc);
  o4.z = f2bf(v.z * sc); o4.w = f2bf(v.w * sc);
  reinterpret_cast<ushort4*>(dst)[t] = o4;
}

// ---------------- K2: 256x128 GEMM (R8-proven loop) + stats epilogue ----------
// 8 waves 4M x 2N, per-wave 64x64 (4x4 16x16x32 frags). No sim store.
// Stats planes: rmax/rE/rE2 [NBX][B_], cmax/cE/cE2 [NBY][B_], diag [B_].
__global__ __launch_bounds__(512, 4) void k_gemm(const unsigned short* __restrict__ A,
                                                 const unsigned short* __restrict__ B,
                                                 float* __restrict__ rmax_p,
                                                 float* __restrict__ rE_p,
                                                 float* __restrict__ rE2_p,
                                                 float* __restrict__ cmax_p,
                                                 float* __restrict__ cE_p,
                                                 float* __restrict__ cE2_p,
                                                 float* __restrict__ diagp) {
  __shared__ unsigned short lds[2][12288];   // [slot][A:0..8192 | B:8192..12288]
  __shared__ float sP[1536];                 // stats combine scratch (6 KB)
  const int tid = threadIdx.x;
  const int wid = tid >> 6;
  const int lane = tid & 63;
  const int wm = wid >> 1;          // 0..3
  const int wn = wid & 1;           // 0..1
  const int bRow = blockIdx.y * BM;
  const int bCol = blockIdx.x * BN;
  const unsigned short* Ag = A + (size_t)bRow * D_;
  const unsigned short* Bg = B + (size_t)bCol * D_;

  // stage geometry (R8, verified 0-conflict)
  const int srowA = wid * 32 + (lane >> 2);
  const int srowB = wid * 16 + (lane >> 2);
  const int scb   = (((lane & 3) ^ ((lane >> 3) & 3))) * 8;
  const size_t soA0 = (size_t)srowA * D_ + scb;
  const size_t soA1 = (size_t)(srowA + 16) * D_ + scb;
  const size_t soB  = (size_t)srowB * D_ + scb;

  // fragment-read geometry (swizzled)
  const int fr = lane & 15;
  const int kq = lane >> 4;
  const int ce = ((kq ^ ((fr >> 1) & 3)) * 8);

  f32x4 acc[4][4] = {};

#define STAGE(T) { const int sl_ = (T) & 1;                                   \
    const unsigned short* gA_ = Ag + (size_t)(T) * BK;                        \
    const unsigned short* gB_ = Bg + (size_t)(T) * BK;                        \
    gload16(gA_ + soA0, &lds[sl_][wid * 1024]);                               \
    gload16(gA_ + soA1, &lds[sl_][wid * 1024 + 512]);                         \
    gload16(gB_ + soB,  &lds[sl_][8192 + wid * 512]); }

  STAGE(0); STAGE(1);
  asm volatile("s_waitcnt vmcnt(3)" ::: "memory");
  __builtin_amdgcn_sched_barrier(0);
  __builtin_amdgcn_s_barrier();
  __builtin_amdgcn_sched_barrier(0);

  for (int t = 0; t < NT; ++t) {
    const unsigned short* Lb = lds[t & 1];
    bf16x8 a[4], b[4];
    #pragma unroll
    for (int m = 0; m < 4; ++m)
      a[m] = *reinterpret_cast<const bf16x8*>(&Lb[(wm*64 + m*16 + fr) * 32 + ce]);
    #pragma unroll
    for (int n = 0; n < 4; ++n)
      b[n] = *reinterpret_cast<const bf16x8*>(&Lb[8192 + (wn*64 + n*16 + fr) * 32 + ce]);
    asm volatile("s_waitcnt lgkmcnt(0)" ::: "memory");
    __builtin_amdgcn_sched_barrier(0);
    __builtin_amdgcn_s_barrier();
    __builtin_amdgcn_sched_barrier(0);
    if (t + 2 < NT) STAGE(t + 2);
    __builtin_amdgcn_s_setprio(1);
    #pragma unroll
    for (int m = 0; m < 4; ++m)
      #pragma unroll
      for (int n = 0; n < 4; ++n)
        acc[m][n] = __builtin_amdgcn_mfma_f32_16x16x32_bf16(a[m], b[n], acc[m][n], 0, 0, 0);
    __builtin_amdgcn_s_setprio(0);
    if (t < NT - 2) {
      asm volatile("s_waitcnt vmcnt(3)" ::: "memory");
    } else if (t == NT - 2) {
      asm volatile("s_waitcnt vmcnt(0)" ::: "memory");
    }
    __builtin_amdgcn_sched_barrier(0);
    if (t < NT - 1) {
      __builtin_amdgcn_s_barrier();
      __builtin_amdgcn_sched_barrier(0);
    }
  }

  // ---- epilogue 1: diag (f32) ----
  const int fr4 = kq * 4;
  #pragma unroll
  for (int m = 0; m < 4; ++m)
    #pragma unroll
    for (int n = 0; n < 4; ++n)
      #pragma unroll
      for (int q = 0; q < 4; ++q) {
        int rg = bRow + wm * 64 + m * 16 + fr4 + q;
        int cg = bCol + wn * 64 + n * 16 + fr;
        if (rg == cg) diagp[rg] = acc[m][n][q];
      }

  // ---- epilogue 2: row stats (per row: max, E=sum exp2(x*KE), E2=sum e*x) ----
  // col accumulators kept live across the pass (cs: 4 cols x 3 stats)
  float csm[4], csE[4], csE2[4];
  #pragma unroll
  for (int n = 0; n < 4; ++n) { csm[n] = -3.4e38f; csE[n] = 0.f; csE2[n] = 0.f; }
  #pragma unroll
  for (int m = 0; m < 4; ++m)
    #pragma unroll
    for (int q = 0; q < 4; ++q) {
      float rm = -3.4e38f, rE = 0.f, rE2 = 0.f;
      #pragma unroll
      for (int n = 0; n < 4; ++n) {
        float x = acc[m][n][q];
        float e = exp2f(x * KE);
        rm = fmaxf(rm, x); rE += e; rE2 = fmaf(e, x, rE2);
        csm[n] = fmaxf(csm[n], x); csE[n] += e; csE2[n] = fmaf(e, x, csE2[n]);
      }
      #pragma unroll
      for (int o = 1; o <= 8; o <<= 1) {
        rm = fmaxf(rm, __shfl_xor(rm, o));
        rE += __shfl_xor(rE, o);
        rE2 += __shfl_xor(rE2, o);
      }
      if (fr == 0) {
        int rl = wm * 64 + m * 16 + fr4 + q;   // 0..255
        sP[wn * 768 + rl] = rm;
        sP[wn * 768 + 256 + rl] = rE;
        sP[wn * 768 + 512 + rl] = rE2;
      }
    }
  __syncthreads();
  if (tid < 256) {
    size_t o = (size_t)blockIdx.x * B_ + bRow + tid;
    rmax_p[o] = fmaxf(sP[tid], sP[768 + tid]);
    rE_p[o]   = sP[256 + tid] + sP[1024 + tid];
    rE2_p[o]  = sP[512 + tid] + sP[1280 + tid];
  }
  __syncthreads();

  // ---- epilogue 3: col stats (reduce kq groups, then 4 wm waves via LDS) ----
  #pragma unroll
  for (int n = 0; n < 4; ++n) {
    float cm = csm[n], cE = csE[n], cE2 = csE2[n];
    #pragma unroll
    for (int o = 16; o <= 32; o <<= 1) {
      cm = fmaxf(cm, __shfl_xor(cm, o));
      cE += __shfl_xor(cE, o);
      cE2 += __shfl_xor(cE2, o);
    }
    if (kq == 0) {
      int cl = wn * 64 + n * 16 + fr;          // 0..127
      if (wm == 0) { sP[cl] = cm; sP[128 + cl] = cE; sP[256 + cl] = cE2; }
      sP[384 + wm * 384 + cl] = cm;            // staged per-wm at 384,768,1152... 
    }
  }
  // simpler: two-step — stage all 4 wm planes then combine
  __syncthreads();
  // (restage cleanly: each wave writes its plane)
  #pragma unroll
  for (int n = 0; n < 4; ++n) {
    float cm = csm[n], cE = csE[n], cE2 = csE2[n];
    #pragma unroll
    for (int o = 16; o <= 32; o <<= 1) {
      cm = fmaxf(cm, __shfl_xor(cm, o));
      cE += __shfl_xor(cE, o);
      cE2 += __shfl_xor(cE2, o);
    }
    if (kq == 0) {
      int cl = wn * 64 + n * 16 + fr;
      sP[wm * 384 + cl] = cm;
      sP[wm * 384 + 128 + cl] = cE;
      sP[wm * 384 + 256 + cl] = cE2;
    }
  }
  __syncthreads();
  if (tid < 128) {
    float cm = fmaxf(fmaxf(sP[tid], sP[384 + tid]),
                     fmaxf(sP[768 + tid], sP[1152 + tid]));
    float cE = (sP[128 + tid] + sP[512 + tid]) + (sP[896 + tid] + sP[1280 + tid]);
    float cE2 = (sP[256 + tid] + sP[640 + tid]) + (sP[1024 + tid] + sP[1408 + tid]);
    size_t o = (size_t)blockIdx.y * B_ + bCol + tid;
    cmax_p[o] = cm; cE_p[o] = cE; cE2_p[o] = cE2;
  }
#undef STAGE
}

// ---------------- K3: reduce partials -> losses -> block partial sums ----------
__global__ __launch_bounds__(256) void k_reduce(
    const float* __restrict__ rmax_p, const float* __restrict__ rE_p,
    const float* __restrict__ rE2_p,  const float* __restrict__ cmax_p,
    const float* __restrict__ cE_p,   const float* __restrict__ cE2_p,
    const float* __restrict__ diag,
    const float* __restrict__ bI, const float* __restrict__ bT,
    const float* __restrict__ sI, const float* __restrict__ sT,
    const int* __restrict__ ids, float* __restrict__ partial) {
  const int t = threadIdx.x;
  const int i = blockIdx.x * 256 + t;
  const float dg = diag[i];
  const int id = ids[i];
  const float ed = exp2f(dg * KE);

  // image (row) side: NBX partials
  float mx = -3.4e38f, E = 0.f, E2 = 0.f;
  for (int p = 0; p < NBX; ++p) {
    size_t o = (size_t)p * B_ + i;
    mx = fmaxf(mx, rmax_p[o]); E += rE_p[o]; E2 += rE2_p[o];
  }
  float oldb = bI[id];
  float newb = fmaxf((mx - dg) * TINV, oldb);
  float sc = exp2f(-(dg * TINV + newb) * LOG2E);
  float S1 = (E - ed) * sc;
  float S2 = (E2 - dg * E) * sc;
  float g = S1 * INV_BM1;
  float sn = 0.2f * sI[id] * exp2f((oldb - newb) * LOG2E) + 0.8f * g;
  float li = S2 / fmaxf(sn, 1e-14f) * INV_BM1;

  // text (col) side: NBY partials
  mx = -3.4e38f; E = 0.f; E2 = 0.f;
  for (int p = 0; p < NBY; ++p) {
    size_t o = (size_t)p * B_ + i;
    mx = fmaxf(mx, cmax_p[o]); E += cE_p[o]; E2 += cE2_p[o];
  }
  oldb = bT[id];
  newb = fmaxf((mx - dg) * TINV, oldb);
  sc = exp2f(-(dg * TINV + newb) * LOG2E);
  S1 = (E - ed) * sc;
  S2 = (E2 - dg * E) * sc;
  g = S1 * INV_BM1;
  sn = 0.2f * sT[id] * exp2f((oldb - newb) * LOG2E) + 0.8f * g;
  float lt = S2 / fmaxf(sn, 1e-14f) * INV_BM1;

  float v = (0.5f * li + 0.5f * lt) * (1.0f / (float)B_);
  #pragma unroll
  for (int o = 32; o >= 1; o >>= 1) v += __shfl_down(v, o);
  __shared__ float red[4];
  if ((t & 63) == 0) red[t >> 6] = v;
  __syncthreads();
  if (t == 0) partial[blockIdx.x] = red[0] + red[1] + red[2] + red[3];
}

__global__ void k_final2(const float* __restrict__ partial, float* __restrict__ out) {
  float v = (threadIdx.x < 16) ? partial[threadIdx.x] : 0.f;
  #pragma unroll
  for (int o = 32; o >= 1; o >>= 1) v += __shfl_down(v, o);
  if (threadIdx.x == 0) out[0] = v;
}

extern "C" void kernel_launch(void* const* d_in, const int* in_sizes, int n_in,
                              void* d_out, int out_size, void* d_ws, size_t ws_size,
                              hipStream_t stream) {
  const float* zis = (const float*)d_in[0];
  const float* zjs = (const float*)d_in[1];
  const float* s_I = (const float*)d_in[2];
  const float* s_T = (const float*)d_in[3];
  const float* b_I = (const float*)d_in[4];
  const float* b_T = (const float*)d_in[5];
  const int*   ids = (const int*)d_in[6];

  char* ws = (char*)d_ws;
  size_t off = 0;
  auto alloc = [&](size_t bytes) -> void* {
    void* p = ws + off;
    off = (off + bytes + 255) & ~(size_t)255;
    return p;
  };
  unsigned short* Abf = (unsigned short*)alloc((size_t)B_ * D_ * 2);   // 8 MB
  unsigned short* Bbf = (unsigned short*)alloc((size_t)B_ * D_ * 2);   // 8 MB
  float* rmax_p = (float*)alloc((size_t)NBX * B_ * 4);                 // 512 KB
  float* rE_p   = (float*)alloc((size_t)NBX * B_ * 4);
  float* rE2_p  = (float*)alloc((size_t)NBX * B_ * 4);
  float* cmax_p = (float*)alloc((size_t)NBY * B_ * 4);                 // 256 KB
  float* cE_p   = (float*)alloc((size_t)NBY * B_ * 4);
  float* cE2_p  = (float*)alloc((size_t)NBY * B_ * 4);
  float* diag   = (float*)alloc(B_ * 4);
  float* partial = (float*)alloc(16 * 4);

  k_normalize<<<2 * B_, 256, 0, stream>>>(zis, zjs, Abf, Bbf);
  k_gemm<<<dim3(B_ / BN, B_ / BM), 512, 0, stream>>>(Abf, Bbf,
      rmax_p, rE_p, rE2_p, cmax_p, cE_p, cE2_p, diag);
  k_reduce<<<16, 256, 0, stream>>>(rmax_p, rE_p, rE2_p, cmax_p, cE_p, cE2_p,
                                   diag, b_I, b_T, s_I, s_T, ids, partial);
  k_final2<<<1, 64, 0, stream>>>(partial, (float*)d_out);
}

// Round 11
// 91.260 us; speedup vs baseline: 1.0969x; 1.0969x over previous
//
#include <hip/hip_runtime.h>
#include <stdint.h>

#define B_ 4096
#define D_ 1024
#define BM 256
#define BN 128
#define BK 32
#define NT 32            // K tiles (1024 / 32)
#define TINV 10.0f
#define LOG2E 1.4426950408889634f
#define KE (TINV * LOG2E)
#define INV_BM1 (1.0f / 4095.0f)

typedef __bf16 bf16x8 __attribute__((ext_vector_type(8)));
typedef float f32x4 __attribute__((ext_vector_type(4)));

__device__ __forceinline__ unsigned short f2bf(float x) {
  uint32_t b = __float_as_uint(x);
  b += 0x7FFF + ((b >> 16) & 1);   // RNE
  return (unsigned short)(b >> 16);
}
__device__ __forceinline__ float bf2f(unsigned short u) {
  return __uint_as_float(((uint32_t)u) << 16);
}

__device__ __forceinline__ void gload16(const void* g, void* l) {
  __builtin_amdgcn_global_load_lds(
      (const __attribute__((address_space(1))) uint32_t*)g,
      (__attribute__((address_space(3))) uint32_t*)l, 16, 0, 0);
}

// ---------------- K1: L2-normalize rows, emit bf16 ----------------
__global__ __launch_bounds__(256) void k_normalize(const float* __restrict__ zis,
                                                   const float* __restrict__ zjs,
                                                   unsigned short* __restrict__ Abf,
                                                   unsigned short* __restrict__ Bbf) {
  int r = blockIdx.x;
  const float* src;
  unsigned short* dst;
  if (r < B_) { src = zis + (size_t)r * D_; dst = Abf + (size_t)r * D_; }
  else        { src = zjs + (size_t)(r - B_) * D_; dst = Bbf + (size_t)(r - B_) * D_; }
  int t = threadIdx.x;
  float4 v = reinterpret_cast<const float4*>(src)[t];
  float ss = v.x*v.x + v.y*v.y + v.z*v.z + v.w*v.w;
  #pragma unroll
  for (int o = 32; o >= 1; o >>= 1) ss += __shfl_down(ss, o);
  __shared__ float red[4];
  if ((t & 63) == 0) red[t >> 6] = ss;
  __syncthreads();
  float sc = rsqrtf(red[0] + red[1] + red[2] + red[3]);
  ushort4 o4;
  o4.x = f2bf(v.x * sc); o4.y = f2bf(v.y * sc);
  o4.z = f2bf(v.z * sc); o4.w = f2bf(v.w * sc);
  reinterpret_cast<ushort4*>(dst)[t] = o4;
}

// ---------------- K2: 256x128 GEMM, BK=32, TRIPLE-buffered LDS (72 KB) -------
// 8 waves 4M x 2N, per-wave 64x64 (4x4 16x16x32 frags). One barrier per tile:
// tile t reads slot t%3; STAGE(t+2) -> slot (t+2)%3 == slot of t-1, whose reads
// are provably retired at the boundary barrier (MFMA lgkm waits). vmcnt(3) at
// each boundary leaves only t+2's 3 loads outstanding.
__global__ __launch_bounds__(512, 4) void k_gemm(const unsigned short* __restrict__ A,
                                                 const unsigned short* __restrict__ B,
                                                 unsigned short* __restrict__ C,
                                                 float* __restrict__ diagp) {
  __shared__ unsigned short lds[3][12288];   // [slot][A:0..8192 | B:8192..12288]
  const int tid = threadIdx.x;
  const int wid = tid >> 6;
  const int lane = tid & 63;
  const int wm = wid >> 1;          // 0..3
  const int wn = wid & 1;           // 0..1
  const int bRow = blockIdx.y * BM;
  const int bCol = blockIdx.x * BN;
  const unsigned short* Ag = A + (size_t)bRow * D_;
  const unsigned short* Bg = B + (size_t)bCol * D_;

  // stage geometry (R8, verified 0-conflict)
  const int srowA = wid * 32 + (lane >> 2);
  const int srowB = wid * 16 + (lane >> 2);
  const int scb   = (((lane & 3) ^ ((lane >> 3) & 3))) * 8;
  const size_t soA0 = (size_t)srowA * D_ + scb;
  const size_t soA1 = (size_t)(srowA + 16) * D_ + scb;
  const size_t soB  = (size_t)srowB * D_ + scb;

  // fragment-read geometry (swizzled, verified 0-conflict)
  const int fr = lane & 15;
  const int kq = lane >> 4;
  const int ce = ((kq ^ ((fr >> 1) & 3)) * 8);

  f32x4 acc[4][4] = {};

#define STAGE(T, SL) {                                                        \
    const unsigned short* gA_ = Ag + (size_t)(T) * BK;                        \
    const unsigned short* gB_ = Bg + (size_t)(T) * BK;                        \
    gload16(gA_ + soA0, &lds[SL][wid * 1024]);                                \
    gload16(gA_ + soA1, &lds[SL][wid * 1024 + 512]);                          \
    gload16(gB_ + soB,  &lds[SL][8192 + wid * 512]); }

  // ---- prologue: stage tiles 0,1 into slots 0,1; drain tile 0 ----
  STAGE(0, 0); STAGE(1, 1);
  asm volatile("s_waitcnt vmcnt(3)" ::: "memory");
  __builtin_amdgcn_sched_barrier(0);
  __builtin_amdgcn_s_barrier();
  __builtin_amdgcn_sched_barrier(0);

  int sl = 0, sl2 = 2;               // sl = t%3 ; sl2 = (t+2)%3
  for (int t = 0; t < NT; ++t) {
    const unsigned short* Lb = lds[sl];
    bf16x8 a[4], b[4];
    #pragma unroll
    for (int m = 0; m < 4; ++m)
      a[m] = *reinterpret_cast<const bf16x8*>(&Lb[(wm*64 + m*16 + fr) * 32 + ce]);
    #pragma unroll
    for (int n = 0; n < 4; ++n)
      b[n] = *reinterpret_cast<const bf16x8*>(&Lb[8192 + (wn*64 + n*16 + fr) * 32 + ce]);
    if (t + 2 < NT) STAGE(t + 2, sl2);   // overwrites slot of t-1 (reads retired)
    __builtin_amdgcn_s_setprio(1);
    #pragma unroll
    for (int m = 0; m < 4; ++m)
      #pragma unroll
      for (int n = 0; n < 4; ++n)
        acc[m][n] = __builtin_amdgcn_mfma_f32_16x16x32_bf16(a[m], b[n], acc[m][n], 0, 0, 0);
    __builtin_amdgcn_s_setprio(0);
    if (t < NT - 2) {
      asm volatile("s_waitcnt vmcnt(3)" ::: "memory");   // t+1 fully staged
    } else if (t == NT - 2) {
      asm volatile("s_waitcnt vmcnt(0)" ::: "memory");
    }
    __builtin_amdgcn_sched_barrier(0);
    if (t < NT - 1) {
      __builtin_amdgcn_s_barrier();
      __builtin_amdgcn_sched_barrier(0);
    }
    sl = (sl == 2) ? 0 : sl + 1;
    sl2 = (sl2 == 2) ? 0 : sl2 + 1;
  }

  // ---- epilogue: diag (f32) + packed bf16x2 C store ----
  const int fr4 = kq * 4;
  #pragma unroll
  for (int m = 0; m < 4; ++m)
    #pragma unroll
    for (int n = 0; n < 4; ++n)
      #pragma unroll
      for (int q = 0; q < 4; ++q) {
        float v = acc[m][n][q];
        int rg = bRow + wm * 64 + m * 16 + fr4 + q;
        int cg = bCol + wn * 64 + n * 16 + fr;
        if (rg == cg) diagp[rg] = v;
        float p = __shfl_xor(v, 1);
        if (!(lane & 1)) {
          uint32_t u = (uint32_t)f2bf(v) | ((uint32_t)f2bf(p) << 16);
          *reinterpret_cast<uint32_t*>(&C[(size_t)rg * B_ + cg]) = u;
        }
      }
#undef STAGE
}

// ---------------- K3: fused single-read pass over bf16 sim ----------------
__global__ __launch_bounds__(256) void k_fused(const unsigned short* __restrict__ sim,
    const float* __restrict__ diag,
    const float* __restrict__ bI, const float* __restrict__ sI,
    const int* __restrict__ ids,
    float* __restrict__ LI, float* __restrict__ cmax_p,
    float* __restrict__ cE_p, float* __restrict__ cE2_p) {
  const int i0 = blockIdx.x * 16;
  const int t = threadIdx.x;
  const int w = t >> 6, lane = t & 63;
  __shared__ float rowPart[16][4][3];

  float cmax[16], cE[16], cE2[16];
  #pragma unroll
  for (int k = 0; k < 16; ++k) { cmax[k] = -3.4e38f; cE[k] = 0.f; cE2[k] = 0.f; }

  for (int r = 0; r < 16; ++r) {
    const unsigned short* sp = sim + (size_t)(i0 + r) * B_ + t * 16;
    uint4 u0 = *reinterpret_cast<const uint4*>(sp);
    uint4 u1 = *reinterpret_cast<const uint4*>(sp + 8);
    float x[16];
    x[0]  = __uint_as_float(u0.x << 16); x[1]  = __uint_as_float(u0.x & 0xffff0000u);
    x[2]  = __uint_as_float(u0.y << 16); x[3]  = __uint_as_float(u0.y & 0xffff0000u);
    x[4]  = __uint_as_float(u0.z << 16); x[5]  = __uint_as_float(u0.z & 0xffff0000u);
    x[6]  = __uint_as_float(u0.w << 16); x[7]  = __uint_as_float(u0.w & 0xffff0000u);
    x[8]  = __uint_as_float(u1.x << 16); x[9]  = __uint_as_float(u1.x & 0xffff0000u);
    x[10] = __uint_as_float(u1.y << 16); x[11] = __uint_as_float(u1.y & 0xffff0000u);
    x[12] = __uint_as_float(u1.z << 16); x[13] = __uint_as_float(u1.z & 0xffff0000u);
    x[14] = __uint_as_float(u1.w << 16); x[15] = __uint_as_float(u1.w & 0xffff0000u);
    float rmx = -3.4e38f, rE = 0.f, rE2 = 0.f;
    #pragma unroll
    for (int k = 0; k < 16; ++k) {
      float e = exp2f(x[k] * KE);
      rmx = fmaxf(rmx, x[k]);
      rE += e;
      rE2 = fmaf(e, x[k], rE2);
      cmax[k] = fmaxf(cmax[k], x[k]);
      cE[k] += e;
      cE2[k] = fmaf(e, x[k], cE2[k]);
    }
    #pragma unroll
    for (int o = 32; o >= 1; o >>= 1) {
      rmx = fmaxf(rmx, __shfl_down(rmx, o));
      rE += __shfl_down(rE, o);
      rE2 += __shfl_down(rE2, o);
    }
    if (lane == 0) { rowPart[r][w][0] = rmx; rowPart[r][w][1] = rE; rowPart[r][w][2] = rE2; }
  }
  __syncthreads();
  if (t < 16) {
    int i = i0 + t;
    float mx = fmaxf(fmaxf(rowPart[t][0][0], rowPart[t][1][0]),
                     fmaxf(rowPart[t][2][0], rowPart[t][3][0]));
    float E  = (rowPart[t][0][1] + rowPart[t][1][1]) + (rowPart[t][2][1] + rowPart[t][3][1]);
    float E2 = (rowPart[t][0][2] + rowPart[t][1][2]) + (rowPart[t][2][2] + rowPart[t][3][2]);
    float dg = diag[i];
    float ed = exp2f(dg * KE);
    int id = ids[i];
    float oldb = bI[id];
    float newb = fmaxf((mx - dg) * TINV, oldb);
    float sc = exp2f(-(dg * TINV + newb) * LOG2E);
    float S1 = (E - ed) * sc;
    float S2 = (E2 - dg * E) * sc;
    float g = S1 * INV_BM1;
    float sn = 0.2f * sI[id] * exp2f((oldb - newb) * LOG2E) + 0.8f * g;
    LI[i] = S2 / fmaxf(sn, 1e-14f) * INV_BM1;
  }
  size_t base = (size_t)blockIdx.x * B_ + t * 16;
  #pragma unroll
  for (int k = 0; k < 16; ++k) {
    cmax_p[base + k] = cmax[k];
    cE_p[base + k]   = cE[k];
    cE2_p[base + k]  = cE2[k];
  }
}

// ---------------- K4: column reduce (512 blocks, 32 threads/col) ----------------
__global__ __launch_bounds__(256) void k_colred(
    const float* __restrict__ diag,
    const float* __restrict__ cmax_p, const float* __restrict__ cE_p,
    const float* __restrict__ cE2_p,
    const float* __restrict__ bT, const float* __restrict__ sT,
    const int* __restrict__ ids, const float* __restrict__ LI,
    float* __restrict__ partial) {
  const int t = threadIdx.x;
  const int cidx = t >> 5;          // 0..7 (col within block)
  const int sub = t & 31;
  const int j = blockIdx.x * 8 + cidx;
  float mx = -3.4e38f, E = 0.f, E2 = 0.f;
  #pragma unroll
  for (int k = 0; k < 8; ++k) {
    size_t o = (size_t)(sub + 32 * k) * B_ + j;
    mx = fmaxf(mx, cmax_p[o]);
    E += cE_p[o];
    E2 += cE2_p[o];
  }
  #pragma unroll
  for (int o = 16; o >= 1; o >>= 1) {
    mx = fmaxf(mx, __shfl_down(mx, o, 32));
    E += __shfl_down(E, o, 32);
    E2 += __shfl_down(E2, o, 32);
  }
  __shared__ float red[8];
  if (sub == 0) {
    float dg = diag[j];
    float ed = exp2f(dg * KE);
    int id = ids[j];
    float oldb = bT[id];
    float newb = fmaxf((mx - dg) * TINV, oldb);
    float sc = exp2f(-(dg * TINV + newb) * LOG2E);
    float S1 = (E - ed) * sc;
    float S2 = (E2 - dg * E) * sc;
    float g = S1 * INV_BM1;
    float sn = 0.2f * sT[id] * exp2f((oldb - newb) * LOG2E) + 0.8f * g;
    float lt = S2 / fmaxf(sn, 1e-14f) * INV_BM1;
    red[cidx] = (0.5f * LI[j] + 0.5f * lt) * (1.0f / (float)B_);
  }
  __syncthreads();
  if (t == 0) {
    float s = 0.f;
    #pragma unroll
    for (int k = 0; k < 8; ++k) s += red[k];
    partial[blockIdx.x] = s;
  }
}

// ---------------- K5: final reduce over 512 partials ----------------
__global__ void k_final2(const float* __restrict__ partial, float* __restrict__ out) {
  int t = threadIdx.x;
  float v = partial[t];
  #pragma unroll
  for (int o = 32; o >= 1; o >>= 1) v += __shfl_down(v, o);
  __shared__ float red[8];
  if ((t & 63) == 0) red[t >> 6] = v;
  __syncthreads();
  if (t == 0) {
    float s = 0.f;
    #pragma unroll
    for (int k = 0; k < 8; ++k) s += red[k];
    out[0] = s;
  }
}

extern "C" void kernel_launch(void* const* d_in, const int* in_sizes, int n_in,
                              void* d_out, int out_size, void* d_ws, size_t ws_size,
                              hipStream_t stream) {
  const float* zis = (const float*)d_in[0];
  const float* zjs = (const float*)d_in[1];
  const float* s_I = (const float*)d_in[2];
  const float* s_T = (const float*)d_in[3];
  const float* b_I = (const float*)d_in[4];
  const float* b_T = (const float*)d_in[5];
  const int*   ids = (const int*)d_in[6];

  char* ws = (char*)d_ws;
  size_t off = 0;
  auto alloc = [&](size_t bytes) -> void* {
    void* p = ws + off;
    off = (off + bytes + 255) & ~(size_t)255;
    return p;
  };
  unsigned short* Abf = (unsigned short*)alloc((size_t)B_ * D_ * 2);   // 8 MB
  unsigned short* Bbf = (unsigned short*)alloc((size_t)B_ * D_ * 2);   // 8 MB
  unsigned short* sim = (unsigned short*)alloc((size_t)B_ * B_ * 2);   // 32 MB
  float* diag   = (float*)alloc(B_ * 4);
  float* cmax_p = (float*)alloc((size_t)256 * B_ * 4);                 // 4 MB each
  float* cE_p   = (float*)alloc((size_t)256 * B_ * 4);
  float* cE2_p  = (float*)alloc((size_t)256 * B_ * 4);
  float* LI     = (float*)alloc(B_ * 4);
  float* partial = (float*)alloc(512 * 4);

  k_normalize<<<2 * B_, 256, 0, stream>>>(zis, zjs, Abf, Bbf);
  k_gemm<<<dim3(B_ / BN, B_ / BM), 512, 0, stream>>>(Abf, Bbf, sim, diag);
  k_fused<<<256, 256, 0, stream>>>(sim, diag, b_I, s_I, ids, LI, cmax_p, cE_p, cE2_p);
  k_colred<<<512, 256, 0, stream>>>(diag, cmax_p, cE_p, cE2_p, b_T, s_T, ids, LI, partial);
  k_final2<<<1, 512, 0, stream>>>(partial, (float*)d_out);
}